// Round 9
// baseline (128.249 us; speedup 1.0000x reference)
//
#include <hip/hip_runtime.h>

typedef float f2 __attribute__((ext_vector_type(2)));
typedef _Float16 half_t;
typedef _Float16 h4 __attribute__((ext_vector_type(4)));
typedef _Float16 h8 __attribute__((ext_vector_type(8)));

// Compile-time filter constants (fold to literals).
static constexpr float REC_LO[12] = {
  0.11154074335008017f, 0.4946238903983854f, 0.7511339080215775f, 0.3152503517092432f,
  -0.22626469396516913f, -0.12976686756709563f, 0.09750160558707936f, 0.02752286553001629f,
  -0.031582039318031156f, 0.0005538422009938016f, 0.004777257511010651f, -0.00107730108499558f };
static constexpr float REC_HI[12] = {
  -0.00107730108499558f, -0.004777257511010651f, 0.0005538422009938016f, 0.031582039318031156f,
  0.02752286553001629f, -0.09750160558707936f, -0.12976686756709563f, 0.22626469396516913f,
  0.3152503517092432f, -0.7511339080215775f, 0.4946238903983854f, -0.11154074335008017f };
static constexpr float DEC_LO[12] = {
  -0.00107730108499558f, 0.004777257511010651f, 0.0005538422009938016f, -0.031582039318031156f,
  0.02752286553001629f, 0.09750160558707936f, -0.12976686756709563f, -0.22626469396516913f,
  0.3152503517092432f, 0.7511339080215775f, 0.4946238903983854f, 0.11154074335008017f };
static constexpr float DEC_HI[12] = {
  -0.11154074335008017f, 0.4946238903983854f, -0.7511339080215775f, 0.3152503517092432f,
  0.22626469396516913f, -0.12976686756709563f, -0.09750160558707936f, 0.02752286553001629f,
  0.031582039318031156f, 0.0005538422009938016f, -0.004777257511010651f, -0.00107730108499558f };

#define NROWS 16384
#define WPB 4  // waves (= rows) per block

// ws layout in HALF elements, per-row strides padded to x8 for 16B alignment:
//  hi0 520@0, hi1 264@520, hi2 144@784, hi3 80@928, hi4 48@1008, hi5 32@1056,
//  hi6 24@1088, hi7 16@1112, loFinal 16@1128.  (mix results now live in LDS.)

// ---------------- Fused 8-level analysis (unchanged from R7) ----------------
__global__ __launch_bounds__(256) void afb_fused(const float* __restrict__ x,
                                                 half_t* __restrict__ ws) {
  __shared__ float sA[WPB][548];
  __shared__ float sB[WPB][296];
  constexpr int LENS[9] = {1024, 517, 264, 137, 74, 42, 26, 18, 14};
  constexpr int HSTR[8] = {520, 264, 144, 80, 48, 32, 24, 16};
  constexpr int HOFF[8] = {0, 520, 784, 928, 1008, 1056, 1088, 1112};
  const int wid = threadIdx.x >> 6;
  const int lane = threadIdx.x & 63;
  const int row = blockIdx.x * WPB + wid;
  float* bufA = sA[wid];
  float* bufB = sB[wid];
  const float* xrow = x + (size_t)row * 1024;
  half_t* hi0 = ws + (size_t)row * 520;

  // ---- Level 0: outputs 0..511, one full-wave pass ----
  {
    const int q = lane;
    const int base = (q == 0) ? 0 : 16 * q - 12;
    float xv[28];
#pragma unroll
    for (int r = 0; r < 7; ++r) {
      float4 v = *reinterpret_cast<const float4*>(xrow + base + 4 * r);
      xv[4 * r] = v.x; xv[4 * r + 1] = v.y; xv[4 * r + 2] = v.z; xv[4 * r + 3] = v.w;
    }
    float w[26];
    if (q == 0) {
#pragma unroll
      for (int e = 0; e < 26; ++e) w[e] = xv[e < 10 ? 9 - e : e - 10];
    } else {
#pragma unroll
      for (int e = 0; e < 26; ++e) w[e] = xv[2 + e];
    }
    f2 a[8];
#pragma unroll
    for (int d = 0; d < 8; ++d) a[d] = (f2){0.f, 0.f};
#pragma unroll
    for (int k = 0; k < 12; ++k) {
      f2 c = (f2){REC_LO[k], REC_HI[k]};
#pragma unroll
      for (int d = 0; d < 8; ++d) a[d] += w[2 * d + k] * c;
    }
#pragma unroll
    for (int d = 0; d < 4; ++d)
      *reinterpret_cast<f2*>(bufA + 14 + 8 * q + 2 * d) = (f2){a[2 * d].x, a[2 * d + 1].x};
    h8 hh;
#pragma unroll
    for (int d = 0; d < 8; ++d) hh[d] = (half_t)a[d].y;
    *reinterpret_cast<h8*>(hi0 + 8 * q) = hh;
  }
  // ---- Level 0 tail: outputs 512..516 on lanes 0..4 ----
  if (lane < 5) {
    const int i0 = 1014 + 2 * lane;
    float acL = 0.f, acH = 0.f;
#pragma unroll
    for (int k = 0; k < 12; ++k) {
      int idx = i0 + k;
      idx = min(idx, 2047 - idx);
      float v = xrow[idx];
      acL += v * REC_LO[k];
      acH += v * REC_HI[k];
    }
    bufA[14 + 512 + lane] = acL;
    hi0[512 + lane] = (half_t)acH;
  }
  if (lane < 21) {  // pads for level-1 input
    int d, s;
    if (lane < 10) { d = 13 - lane; s = 14 + lane; }
    else { int k = lane - 10; d = 14 + 517 + k; s = 14 + 516 - k; }
    bufA[d] = bufA[s];
  }

  // ---- Level 1: chunk-8, 33 lanes (264 = 33*8 exact) ----
  if (lane < 33) {
    const float* pp = bufA + 16 * lane + 4;
    float xv[28];
#pragma unroll
    for (int r = 0; r < 7; ++r) {
      float4 v = *reinterpret_cast<const float4*>(pp + 4 * r);
      xv[4 * r] = v.x; xv[4 * r + 1] = v.y; xv[4 * r + 2] = v.z; xv[4 * r + 3] = v.w;
    }
    f2 a[8];
#pragma unroll
    for (int d = 0; d < 8; ++d) a[d] = (f2){0.f, 0.f};
#pragma unroll
    for (int k = 0; k < 12; ++k) {
      f2 c = (f2){REC_LO[k], REC_HI[k]};
#pragma unroll
      for (int d = 0; d < 8; ++d) a[d] += xv[2 * d + k] * c;
    }
#pragma unroll
    for (int d = 0; d < 4; ++d)
      *reinterpret_cast<f2*>(bufB + 14 + 8 * lane + 2 * d) = (f2){a[2 * d].x, a[2 * d + 1].x};
    h8 hh;
#pragma unroll
    for (int d = 0; d < 8; ++d) hh[d] = (half_t)a[d].y;
    *reinterpret_cast<h8*>(ws + (size_t)NROWS * 520 + (size_t)row * 264 + 8 * lane) = hh;
  }
  if (lane < 21) {  // pads for level-2 input
    int d, s;
    if (lane < 10) { d = 13 - lane; s = 14 + lane; }
    else { int k = lane - 10; d = 14 + 264 + k; s = 14 + 263 - k; }
    bufB[d] = bufB[s];
  }

  __syncthreads();
  if (wid != 0) return;

  // ---- Phase 2 (wave 0): levels 2..7 for 4 rows, 16-lane groups ----
  const int sub = lane >> 4, l16 = lane & 15;
  const int prow = blockIdx.x * WPB + sub;
  float* cur = sB[sub];
  float* dst = sA[sub];
  constexpr int NITS[8] = {0, 0, 3, 2, 1, 1, 1, 1};
#pragma unroll
  for (int j = 2; j < 8; ++j) {
    const int outN = LENS[j + 1];
    const int NCH = (outN + 3) / 4;
    half_t* hiRow = ws + (size_t)NROWS * HOFF[j] + (size_t)prow * HSTR[j];
#pragma unroll
    for (int it = 0; it < NITS[j]; ++it) {
      const int q = it * 16 + l16;
      if (q < NCH) {
        const float* pp = cur + 8 * q + 4;
        float xv[20];
#pragma unroll
        for (int r = 0; r < 5; ++r) {
          float4 v = *reinterpret_cast<const float4*>(pp + 4 * r);
          xv[4 * r] = v.x; xv[4 * r + 1] = v.y; xv[4 * r + 2] = v.z; xv[4 * r + 3] = v.w;
        }
        f2 a0 = {0.f, 0.f}, a1 = {0.f, 0.f}, a2 = {0.f, 0.f}, a3 = {0.f, 0.f};
#pragma unroll
        for (int k = 0; k < 12; ++k) {
          f2 c = (f2){REC_LO[k], REC_HI[k]};
          a0 += xv[k] * c; a1 += xv[2 + k] * c; a2 += xv[4 + k] * c; a3 += xv[6 + k] * c;
        }
        if (j < 7) {
          *reinterpret_cast<f2*>(dst + 14 + 4 * q) = (f2){a0.x, a1.x};
          *reinterpret_cast<f2*>(dst + 16 + 4 * q) = (f2){a2.x, a3.x};
        } else {
          h4 hl; hl[0] = (half_t)a0.x; hl[1] = (half_t)a1.x; hl[2] = (half_t)a2.x; hl[3] = (half_t)a3.x;
          *reinterpret_cast<h4*>(ws + (size_t)NROWS * 1128 + (size_t)prow * 16 + 4 * q) = hl;
        }
        h4 hh; hh[0] = (half_t)a0.y; hh[1] = (half_t)a1.y; hh[2] = (half_t)a2.y; hh[3] = (half_t)a3.y;
        *reinterpret_cast<h4*>(hiRow + 4 * q) = hh;
      }
    }
    if (j < 7) {
      if (l16 < 10) dst[13 - l16] = dst[14 + l16];
      if (l16 < 11) dst[14 + outN + l16] = dst[14 + outN - 1 - l16];
      float* t = cur; cur = dst; dst = t;
    }
  }
}

// ---------------- Fused synthesis + in-kernel channel mix ----------------
// Phase 0 (wave 0, lanes 0-31): both einsums for this block's batch/channels;
// 64-deep dots, fp32 accumulate, results to LDS (loM/hmS) -- no fp16 round-trip.
// Lanes 32-63 zero the ghost slack. Phase 1 (wave 0): s=0 from LDS, s=1..5 from
// global fp16, 16-lane groups per row. Phase 2 (all waves): s=6 (64 chunks +
// 3-lane tail), s=7 (2x64 exact).
__global__ __launch_bounds__(256) void sfb_fused(const half_t* __restrict__ ws,
                                                 const float* __restrict__ w1,
                                                 const float* __restrict__ w2,
                                                 float* __restrict__ out) {
  __shared__ float sP[WPB][280];
  __shared__ float sQ[WPB][544];
  __shared__ float loM[WPB][20];
  __shared__ float hmS[WPB][20];
  const int wid = threadIdx.x >> 6;
  const int lane = threadIdx.x & 63;

  if (wid == 0) {
    // ---- Phase 0: channel mix for this block's 4 rows (same batch b) ----
    const int row0 = blockIdx.x * WPB;
    if (lane < 32) {
      const int kind = lane >> 4;       // 0: loFinal*w1, 1: hi7*w2
      const int c = (lane >> 2) & 3;    // block-local channel 0..3
      const int xg = lane & 3;          // x-group of 4
      const int b = row0 >> 6;
      const int cg = (row0 & 63) + c;   // global output channel
      const half_t* inb = ws + (size_t)NROWS * (kind ? 1112 : 1128) + (size_t)(b * 64) * 16 + 4 * xg;
      const float* wb = (kind ? w2 : w1) + cg * 14 + 4 * xg;
      float a0 = 0.f, a1 = 0.f, a2 = 0.f, a3 = 0.f;
#pragma unroll 8
      for (int i = 0; i < 64; ++i) {
        h4 iv = *reinterpret_cast<const h4*>(inb + (size_t)i * 16);
        const float* wp = wb + (size_t)i * 896;
        if (xg < 3) {
          float4 wv = *reinterpret_cast<const float4*>(wp);
          a0 += (float)iv[0] * wv.x; a1 += (float)iv[1] * wv.y;
          a2 += (float)iv[2] * wv.z; a3 += (float)iv[3] * wv.w;
        } else {  // x = 12,13 only (stay in-bounds of w)
          f2 wv = *reinterpret_cast<const f2*>(wp);
          a0 += (float)iv[0] * wv.x; a1 += (float)iv[1] * wv.y;
        }
      }
      float* o = (kind ? hmS[c] : loM[c]) + 4 * xg;
      o[0] = a0; o[1] = a1; o[2] = a2; o[3] = a3;  // xg=3: positions 14,15 get 0
    } else {
      int t = lane - 32;  // zero ghost slack [16..19]
      if (t < 16) loM[t >> 2][16 + (t & 3)] = 0.f;
      else { t -= 16; hmS[(t - 16) >> 2][16 + ((t - 16) & 3)] = 0.f; }
    }

    // ---- Phase 1: s=0..5 for 4 rows, 16-lane groups ----
    const int sub = lane >> 4, l16 = lane & 15;
    const int prow = row0 + sub;
    float* cur;
    float* dst = sQ[sub];
    // s = 0: N=14, NP=9, PCH=3; lo/hi from LDS f32
    if (l16 < 3) {
      const int m0 = 4 * l16;
      float lv[9], hv[9];
#pragma unroll
      for (int e = 0; e < 9; ++e) { lv[e] = loM[sub][m0 + e]; hv[e] = hmS[sub][m0 + e]; }
      f2 a0 = {0.f, 0.f}, a1 = {0.f, 0.f}, a2 = {0.f, 0.f}, a3 = {0.f, 0.f};
#pragma unroll
      for (int t = 0; t < 6; ++t) {
        f2 dl = (f2){DEC_LO[2 * t + 1], DEC_LO[2 * t]};
        f2 dh = (f2){DEC_HI[2 * t + 1], DEC_HI[2 * t]};
        a0 += lv[t] * dl + hv[t] * dh;
        a1 += lv[1 + t] * dl + hv[1 + t] * dh;
        a2 += lv[2 + t] * dl + hv[2 + t] * dh;
        a3 += lv[3 + t] * dl + hv[3 + t] * dh;
      }
      *reinterpret_cast<float4*>(dst + 2 * m0)     = make_float4(a0.x, a0.y, a1.x, a1.y);
      *reinterpret_cast<float4*>(dst + 2 * m0 + 4) = make_float4(a2.x, a2.y, a3.x, a3.y);
    }
    cur = sQ[sub];
    dst = sP[sub];
    // s = 1..5 from global fp16 hi
    constexpr int LENSY2[5] = {18, 26, 42, 74, 137};
    constexpr int HSOFF2[5] = {1088, 1056, 1008, 928, 784};  // hi6..hi2
    constexpr int HSSTR2[5] = {24, 32, 48, 80, 144};
    constexpr int NITS2[5] = {1, 1, 1, 2, 3};
#pragma unroll
    for (int s = 0; s < 5; ++s) {
      const int N = LENSY2[s];
      const int NP = N - 5;
      const int PCH = (NP + 3) / 4;
      const half_t* hsrc = ws + (size_t)NROWS * HSOFF2[s] + (size_t)prow * HSSTR2[s];
#pragma unroll
      for (int it = 0; it < NITS2[s]; ++it) {
        const int q = it * 16 + l16;
        if (q < PCH) {
          const int m0 = 4 * q;
          float lv[9];
          {
            float4 a = *reinterpret_cast<const float4*>(cur + m0);
            float4 b = *reinterpret_cast<const float4*>(cur + m0 + 4);
            lv[0] = a.x; lv[1] = a.y; lv[2] = a.z; lv[3] = a.w;
            lv[4] = b.x; lv[5] = b.y; lv[6] = b.z; lv[7] = b.w;
            lv[8] = cur[m0 + 8];
          }
          float hv[9];
          {
            h4 h0 = *reinterpret_cast<const h4*>(hsrc + m0);
            h4 h1 = *reinterpret_cast<const h4*>(hsrc + m0 + 4);
            half_t h2 = hsrc[m0 + 8];
            hv[0] = (float)h0[0]; hv[1] = (float)h0[1]; hv[2] = (float)h0[2]; hv[3] = (float)h0[3];
            hv[4] = (float)h1[0]; hv[5] = (float)h1[1]; hv[6] = (float)h1[2]; hv[7] = (float)h1[3];
            hv[8] = (float)h2;
          }
          f2 a0 = {0.f, 0.f}, a1 = {0.f, 0.f}, a2 = {0.f, 0.f}, a3 = {0.f, 0.f};
#pragma unroll
          for (int t = 0; t < 6; ++t) {
            f2 dl = (f2){DEC_LO[2 * t + 1], DEC_LO[2 * t]};
            f2 dh = (f2){DEC_HI[2 * t + 1], DEC_HI[2 * t]};
            a0 += lv[t] * dl + hv[t] * dh;
            a1 += lv[1 + t] * dl + hv[1 + t] * dh;
            a2 += lv[2 + t] * dl + hv[2 + t] * dh;
            a3 += lv[3 + t] * dl + hv[3 + t] * dh;
          }
          *reinterpret_cast<float4*>(dst + 2 * m0)     = make_float4(a0.x, a0.y, a1.x, a1.y);
          *reinterpret_cast<float4*>(dst + 2 * m0 + 4) = make_float4(a2.x, a2.y, a3.x, a3.y);
        }
      }
      float* t = cur; cur = dst; dst = t;
    }
    // after s=0..5: y6 lives in sP[sub]
  }
  __syncthreads();

  // ---- Phase 2: all waves, own row ----
  const int row = blockIdx.x * WPB + wid;
  float* cur = sP[wid];
  float* dst = sQ[wid];
  // s = 6: N=264, NP=259: one unmasked 64-chunk pass (pairs 0..255)
  {
    const half_t* hsrc = ws + (size_t)NROWS * 520 + (size_t)row * 264;  // hi1
    const int m0 = 4 * lane;
    float lv[9];
    {
      float4 a = *reinterpret_cast<const float4*>(cur + m0);
      float4 b = *reinterpret_cast<const float4*>(cur + m0 + 4);
      lv[0] = a.x; lv[1] = a.y; lv[2] = a.z; lv[3] = a.w;
      lv[4] = b.x; lv[5] = b.y; lv[6] = b.z; lv[7] = b.w;
      lv[8] = cur[m0 + 8];
    }
    float hv[9];
    {
      h4 h0 = *reinterpret_cast<const h4*>(hsrc + m0);
      h4 h1 = *reinterpret_cast<const h4*>(hsrc + m0 + 4);
      half_t h2 = hsrc[m0 + 8];
      hv[0] = (float)h0[0]; hv[1] = (float)h0[1]; hv[2] = (float)h0[2]; hv[3] = (float)h0[3];
      hv[4] = (float)h1[0]; hv[5] = (float)h1[1]; hv[6] = (float)h1[2]; hv[7] = (float)h1[3];
      hv[8] = (float)h2;
    }
    f2 a0 = {0.f, 0.f}, a1 = {0.f, 0.f}, a2 = {0.f, 0.f}, a3 = {0.f, 0.f};
#pragma unroll
    for (int t = 0; t < 6; ++t) {
      f2 dl = (f2){DEC_LO[2 * t + 1], DEC_LO[2 * t]};
      f2 dh = (f2){DEC_HI[2 * t + 1], DEC_HI[2 * t]};
      a0 += lv[t] * dl + hv[t] * dh;
      a1 += lv[1 + t] * dl + hv[1 + t] * dh;
      a2 += lv[2 + t] * dl + hv[2 + t] * dh;
      a3 += lv[3 + t] * dl + hv[3 + t] * dh;
    }
    *reinterpret_cast<float4*>(dst + 2 * m0)     = make_float4(a0.x, a0.y, a1.x, a1.y);
    *reinterpret_cast<float4*>(dst + 2 * m0 + 4) = make_float4(a2.x, a2.y, a3.x, a3.y);
    // tail: pairs 256..258 on lanes 0..2 (scalar form)
    if (lane < 3) {
      const int m = 256 + lane;
      float aE = 0.f, aO = 0.f;
#pragma unroll
      for (int t = 0; t < 6; ++t) {
        float lvv = cur[m + t];
        float hvv = (float)hsrc[m + t];
        aE += lvv * DEC_LO[2 * t + 1] + hvv * DEC_HI[2 * t + 1];
        aO += lvv * DEC_LO[2 * t]     + hvv * DEC_HI[2 * t];
      }
      *reinterpret_cast<f2*>(dst + 2 * m) = (f2){aE, aO};
    }
  }
  // s = 7: N=517, NP=512, 2x64 exact (no masks)
  {
    const half_t* hsrc = ws + (size_t)row * 520;  // hi0
    float* orow = out + (size_t)row * 1024;
#pragma unroll
    for (int q0 = 0; q0 < 128; q0 += 64) {
      const int m0 = 4 * (q0 + lane);
      float lv[9];
      {
        float4 a = *reinterpret_cast<const float4*>(dst + m0);
        float4 b = *reinterpret_cast<const float4*>(dst + m0 + 4);
        lv[0] = a.x; lv[1] = a.y; lv[2] = a.z; lv[3] = a.w;
        lv[4] = b.x; lv[5] = b.y; lv[6] = b.z; lv[7] = b.w;
        lv[8] = dst[m0 + 8];
      }
      float hv[9];
      {
        h4 h0 = *reinterpret_cast<const h4*>(hsrc + m0);
        h4 h1 = *reinterpret_cast<const h4*>(hsrc + m0 + 4);
        half_t h2 = hsrc[m0 + 8];
        hv[0] = (float)h0[0]; hv[1] = (float)h0[1]; hv[2] = (float)h0[2]; hv[3] = (float)h0[3];
        hv[4] = (float)h1[0]; hv[5] = (float)h1[1]; hv[6] = (float)h1[2]; hv[7] = (float)h1[3];
        hv[8] = (float)h2;
      }
      f2 a0 = {0.f, 0.f}, a1 = {0.f, 0.f}, a2 = {0.f, 0.f}, a3 = {0.f, 0.f};
#pragma unroll
      for (int t = 0; t < 6; ++t) {
        f2 dl = (f2){DEC_LO[2 * t + 1], DEC_LO[2 * t]};
        f2 dh = (f2){DEC_HI[2 * t + 1], DEC_HI[2 * t]};
        a0 += lv[t] * dl + hv[t] * dh;
        a1 += lv[1 + t] * dl + hv[1 + t] * dh;
        a2 += lv[2 + t] * dl + hv[2 + t] * dh;
        a3 += lv[3 + t] * dl + hv[3 + t] * dh;
      }
      *reinterpret_cast<float4*>(orow + 2 * m0)     = make_float4(a0.x, a0.y, a1.x, a1.y);
      *reinterpret_cast<float4*>(orow + 2 * m0 + 4) = make_float4(a2.x, a2.y, a3.x, a3.y);
    }
  }
}

extern "C" void kernel_launch(void* const* d_in, const int* in_sizes, int n_in,
                              void* d_out, int out_size, void* d_ws, size_t ws_size,
                              hipStream_t stream) {
  (void)in_sizes; (void)n_in; (void)out_size; (void)ws_size;
  const float* x  = (const float*)d_in[0];
  const float* w1 = (const float*)d_in[1];
  const float* w2 = (const float*)d_in[2];
  float* out = (float*)d_out;
  half_t* ws = (half_t*)d_ws;

  afb_fused<<<NROWS / WPB, 64 * WPB, 0, stream>>>(x, ws);
  sfb_fused<<<NROWS / WPB, 64 * WPB, 0, stream>>>(ws, w1, w2, out);
}

// Round 10
// 62.640 us; speedup vs baseline: 2.0474x; 2.0474x over previous
//
#include <hip/hip_runtime.h>

typedef float f2 __attribute__((ext_vector_type(2)));
typedef _Float16 half_t;
typedef _Float16 h4 __attribute__((ext_vector_type(4)));
typedef _Float16 h8 __attribute__((ext_vector_type(8)));

// Compile-time filter constants (fold to literals).
static constexpr float REC_LO[12] = {
  0.11154074335008017f, 0.4946238903983854f, 0.7511339080215775f, 0.3152503517092432f,
  -0.22626469396516913f, -0.12976686756709563f, 0.09750160558707936f, 0.02752286553001629f,
  -0.031582039318031156f, 0.0005538422009938016f, 0.004777257511010651f, -0.00107730108499558f };
static constexpr float REC_HI[12] = {
  -0.00107730108499558f, -0.004777257511010651f, 0.0005538422009938016f, 0.031582039318031156f,
  0.02752286553001629f, -0.09750160558707936f, -0.12976686756709563f, 0.22626469396516913f,
  0.3152503517092432f, -0.7511339080215775f, 0.4946238903983854f, -0.11154074335008017f };
static constexpr float DEC_LO[12] = {
  -0.00107730108499558f, 0.004777257511010651f, 0.0005538422009938016f, -0.031582039318031156f,
  0.02752286553001629f, 0.09750160558707936f, -0.12976686756709563f, -0.22626469396516913f,
  0.3152503517092432f, 0.7511339080215775f, 0.4946238903983854f, 0.11154074335008017f };
static constexpr float DEC_HI[12] = {
  -0.11154074335008017f, 0.4946238903983854f, -0.7511339080215775f, 0.3152503517092432f,
  0.22626469396516913f, -0.12976686756709563f, -0.09750160558707936f, 0.02752286553001629f,
  0.031582039318031156f, 0.0005538422009938016f, -0.004777257511010651f, -0.00107730108499558f };

#define NROWS 16384
#define WPB 4  // waves (= rows) per block

// ws layout in HALF elements, per-row strides padded to x8 for 16B alignment:
//  hi0 520@0, hi1 264@520, hi2 144@784, hi3 80@928, hi4 48@1008, hi5 32@1056,
//  hi6 24@1088, hi7 16@1112, loFinal 16@1128, hm 16@1144, loMixed 16@1160.

// ---------------- Fused 8-level analysis (R7-proven) ----------------
__global__ __launch_bounds__(256) void afb_fused(const float* __restrict__ x,
                                                 half_t* __restrict__ ws) {
  __shared__ float sA[WPB][548];
  __shared__ float sB[WPB][296];
  constexpr int LENS[9] = {1024, 517, 264, 137, 74, 42, 26, 18, 14};
  constexpr int HSTR[8] = {520, 264, 144, 80, 48, 32, 24, 16};
  constexpr int HOFF[8] = {0, 520, 784, 928, 1008, 1056, 1088, 1112};
  const int wid = threadIdx.x >> 6;
  const int lane = threadIdx.x & 63;
  const int row = blockIdx.x * WPB + wid;
  float* bufA = sA[wid];
  float* bufB = sB[wid];
  const float* xrow = x + (size_t)row * 1024;
  half_t* hi0 = ws + (size_t)row * 520;

  // ---- Level 0: outputs 0..511, one full-wave pass ----
  {
    const int q = lane;
    const int base = (q == 0) ? 0 : 16 * q - 12;
    float xv[28];
#pragma unroll
    for (int r = 0; r < 7; ++r) {
      float4 v = *reinterpret_cast<const float4*>(xrow + base + 4 * r);
      xv[4 * r] = v.x; xv[4 * r + 1] = v.y; xv[4 * r + 2] = v.z; xv[4 * r + 3] = v.w;
    }
    float w[26];
    if (q == 0) {
#pragma unroll
      for (int e = 0; e < 26; ++e) w[e] = xv[e < 10 ? 9 - e : e - 10];
    } else {
#pragma unroll
      for (int e = 0; e < 26; ++e) w[e] = xv[2 + e];
    }
    f2 a[8];
#pragma unroll
    for (int d = 0; d < 8; ++d) a[d] = (f2){0.f, 0.f};
#pragma unroll
    for (int k = 0; k < 12; ++k) {
      f2 c = (f2){REC_LO[k], REC_HI[k]};
#pragma unroll
      for (int d = 0; d < 8; ++d) a[d] += w[2 * d + k] * c;
    }
#pragma unroll
    for (int d = 0; d < 4; ++d)
      *reinterpret_cast<f2*>(bufA + 14 + 8 * q + 2 * d) = (f2){a[2 * d].x, a[2 * d + 1].x};
    h8 hh;
#pragma unroll
    for (int d = 0; d < 8; ++d) hh[d] = (half_t)a[d].y;
    *reinterpret_cast<h8*>(hi0 + 8 * q) = hh;
  }
  // ---- Level 0 tail: outputs 512..516 on lanes 0..4 ----
  if (lane < 5) {
    const int i0 = 1014 + 2 * lane;
    float acL = 0.f, acH = 0.f;
#pragma unroll
    for (int k = 0; k < 12; ++k) {
      int idx = i0 + k;
      idx = min(idx, 2047 - idx);
      float v = xrow[idx];
      acL += v * REC_LO[k];
      acH += v * REC_HI[k];
    }
    bufA[14 + 512 + lane] = acL;
    hi0[512 + lane] = (half_t)acH;
  }
  if (lane < 21) {  // pads for level-1 input
    int d, s;
    if (lane < 10) { d = 13 - lane; s = 14 + lane; }
    else { int k = lane - 10; d = 14 + 517 + k; s = 14 + 516 - k; }
    bufA[d] = bufA[s];
  }

  // ---- Level 1: chunk-8, 33 lanes (264 = 33*8 exact) ----
  if (lane < 33) {
    const float* pp = bufA + 16 * lane + 4;
    float xv[28];
#pragma unroll
    for (int r = 0; r < 7; ++r) {
      float4 v = *reinterpret_cast<const float4*>(pp + 4 * r);
      xv[4 * r] = v.x; xv[4 * r + 1] = v.y; xv[4 * r + 2] = v.z; xv[4 * r + 3] = v.w;
    }
    f2 a[8];
#pragma unroll
    for (int d = 0; d < 8; ++d) a[d] = (f2){0.f, 0.f};
#pragma unroll
    for (int k = 0; k < 12; ++k) {
      f2 c = (f2){REC_LO[k], REC_HI[k]};
#pragma unroll
      for (int d = 0; d < 8; ++d) a[d] += xv[2 * d + k] * c;
    }
#pragma unroll
    for (int d = 0; d < 4; ++d)
      *reinterpret_cast<f2*>(bufB + 14 + 8 * lane + 2 * d) = (f2){a[2 * d].x, a[2 * d + 1].x};
    h8 hh;
#pragma unroll
    for (int d = 0; d < 8; ++d) hh[d] = (half_t)a[d].y;
    *reinterpret_cast<h8*>(ws + (size_t)NROWS * 520 + (size_t)row * 264 + 8 * lane) = hh;
  }
  if (lane < 21) {  // pads for level-2 input
    int d, s;
    if (lane < 10) { d = 13 - lane; s = 14 + lane; }
    else { int k = lane - 10; d = 14 + 264 + k; s = 14 + 263 - k; }
    bufB[d] = bufB[s];
  }

  __syncthreads();
  if (wid != 0) return;

  // ---- Phase 2 (wave 0): levels 2..7 for 4 rows, 16-lane groups ----
  const int sub = lane >> 4, l16 = lane & 15;
  const int prow = blockIdx.x * WPB + sub;
  float* cur = sB[sub];
  float* dst = sA[sub];
  constexpr int NITS[8] = {0, 0, 3, 2, 1, 1, 1, 1};
#pragma unroll
  for (int j = 2; j < 8; ++j) {
    const int outN = LENS[j + 1];
    const int NCH = (outN + 3) / 4;
    half_t* hiRow = ws + (size_t)NROWS * HOFF[j] + (size_t)prow * HSTR[j];
#pragma unroll
    for (int it = 0; it < NITS[j]; ++it) {
      const int q = it * 16 + l16;
      if (q < NCH) {
        const float* pp = cur + 8 * q + 4;
        float xv[20];
#pragma unroll
        for (int r = 0; r < 5; ++r) {
          float4 v = *reinterpret_cast<const float4*>(pp + 4 * r);
          xv[4 * r] = v.x; xv[4 * r + 1] = v.y; xv[4 * r + 2] = v.z; xv[4 * r + 3] = v.w;
        }
        f2 a0 = {0.f, 0.f}, a1 = {0.f, 0.f}, a2 = {0.f, 0.f}, a3 = {0.f, 0.f};
#pragma unroll
        for (int k = 0; k < 12; ++k) {
          f2 c = (f2){REC_LO[k], REC_HI[k]};
          a0 += xv[k] * c; a1 += xv[2 + k] * c; a2 += xv[4 + k] * c; a3 += xv[6 + k] * c;
        }
        if (j < 7) {
          *reinterpret_cast<f2*>(dst + 14 + 4 * q) = (f2){a0.x, a1.x};
          *reinterpret_cast<f2*>(dst + 16 + 4 * q) = (f2){a2.x, a3.x};
        } else {
          h4 hl; hl[0] = (half_t)a0.x; hl[1] = (half_t)a1.x; hl[2] = (half_t)a2.x; hl[3] = (half_t)a3.x;
          *reinterpret_cast<h4*>(ws + (size_t)NROWS * 1128 + (size_t)prow * 16 + 4 * q) = hl;
        }
        h4 hh; hh[0] = (half_t)a0.y; hh[1] = (half_t)a1.y; hh[2] = (half_t)a2.y; hh[3] = (half_t)a3.y;
        *reinterpret_cast<h4*>(hiRow + 4 * q) = hh;
      }
    }
    if (j < 7) {
      if (l16 < 10) dst[13 - l16] = dst[14 + l16];
      if (l16 < 11) dst[14 + outN + l16] = dst[14 + outN - 1 - l16];
      float* t = cur; cur = dst; dst = t;
    }
  }
}

// ---------------- Fused 8-level synthesis (R7-proven + s=6 tail-merge) ----------------
__global__ __launch_bounds__(256) void sfb_fused(const half_t* __restrict__ ws,
                                                 float* __restrict__ out) {
  __shared__ float sP[WPB][280];  // y0,y2,y4,y6 (max read idx 267)
  __shared__ float sQ[WPB][544];  // y1,y3,y5,y7 (max write idx 517)
  const int wid = threadIdx.x >> 6;
  const int lane = threadIdx.x & 63;

  if (wid == 0) {
    constexpr int LENSY[6] = {14, 18, 26, 42, 74, 137};
    constexpr int HSOFF[6] = {1144, 1088, 1056, 1008, 928, 784};  // hm, hi6..hi2
    constexpr int HSSTR[6] = {16, 24, 32, 48, 80, 144};
    constexpr int NITS[6] = {1, 1, 1, 1, 2, 3};
    const int sub = lane >> 4, l16 = lane & 15;
    const int prow = blockIdx.x * WPB + sub;
    float* cur = sP[sub];
    float* dst = sQ[sub];
    if (l16 < 2) {  // y0 = loMixed (14 valid; 14,15 ghost-only)
      h8 v = *reinterpret_cast<const h8*>(ws + (size_t)NROWS * 1160 + (size_t)prow * 16 + 8 * l16);
      *reinterpret_cast<float4*>(cur + 8 * l16) =
          make_float4((float)v[0], (float)v[1], (float)v[2], (float)v[3]);
      *reinterpret_cast<float4*>(cur + 8 * l16 + 4) =
          make_float4((float)v[4], (float)v[5], (float)v[6], (float)v[7]);
    }
#pragma unroll
    for (int s = 0; s < 6; ++s) {
      const int N = LENSY[s];
      const int NP = N - 5;
      const int PCH = (NP + 3) / 4;
      const half_t* hsrc = ws + (size_t)NROWS * HSOFF[s] + (size_t)prow * HSSTR[s];
#pragma unroll
      for (int it = 0; it < NITS[s]; ++it) {
        const int q = it * 16 + l16;
        if (q < PCH) {
          const int m0 = 4 * q;
          float lv[9];
          {
            float4 a = *reinterpret_cast<const float4*>(cur + m0);
            float4 b = *reinterpret_cast<const float4*>(cur + m0 + 4);
            lv[0] = a.x; lv[1] = a.y; lv[2] = a.z; lv[3] = a.w;
            lv[4] = b.x; lv[5] = b.y; lv[6] = b.z; lv[7] = b.w;
            lv[8] = cur[m0 + 8];
          }
          float hv[9];
          {
            h4 h0 = *reinterpret_cast<const h4*>(hsrc + m0);
            h4 h1 = *reinterpret_cast<const h4*>(hsrc + m0 + 4);
            half_t h2 = hsrc[m0 + 8];
            hv[0] = (float)h0[0]; hv[1] = (float)h0[1]; hv[2] = (float)h0[2]; hv[3] = (float)h0[3];
            hv[4] = (float)h1[0]; hv[5] = (float)h1[1]; hv[6] = (float)h1[2]; hv[7] = (float)h1[3];
            hv[8] = (float)h2;
          }
          f2 a0 = {0.f, 0.f}, a1 = {0.f, 0.f}, a2 = {0.f, 0.f}, a3 = {0.f, 0.f};
#pragma unroll
          for (int t = 0; t < 6; ++t) {
            f2 dl = (f2){DEC_LO[2 * t + 1], DEC_LO[2 * t]};
            f2 dh = (f2){DEC_HI[2 * t + 1], DEC_HI[2 * t]};
            a0 += lv[t] * dl + hv[t] * dh;
            a1 += lv[1 + t] * dl + hv[1 + t] * dh;
            a2 += lv[2 + t] * dl + hv[2 + t] * dh;
            a3 += lv[3 + t] * dl + hv[3 + t] * dh;
          }
          *reinterpret_cast<float4*>(dst + 2 * m0)     = make_float4(a0.x, a0.y, a1.x, a1.y);
          *reinterpret_cast<float4*>(dst + 2 * m0 + 4) = make_float4(a2.x, a2.y, a3.x, a3.y);
        }
      }
      float* t = cur; cur = dst; dst = t;
    }
    // after 6 swaps: y6 lives in sP[sub]
  }
  __syncthreads();

  // ---- Phase 2: all waves, own row ----
  const int row = blockIdx.x * WPB + wid;
  float* cur = sP[wid];
  float* dst = sQ[wid];
  // s = 6: N=264, NP=259: one unmasked 64-chunk pass (pairs 0..255) + 3-lane tail
  {
    const half_t* hsrc = ws + (size_t)NROWS * 520 + (size_t)row * 264;  // hi1
    const int m0 = 4 * lane;
    float lv[9];
    {
      float4 a = *reinterpret_cast<const float4*>(cur + m0);
      float4 b = *reinterpret_cast<const float4*>(cur + m0 + 4);
      lv[0] = a.x; lv[1] = a.y; lv[2] = a.z; lv[3] = a.w;
      lv[4] = b.x; lv[5] = b.y; lv[6] = b.z; lv[7] = b.w;
      lv[8] = cur[m0 + 8];
    }
    float hv[9];
    {
      h4 h0 = *reinterpret_cast<const h4*>(hsrc + m0);
      h4 h1 = *reinterpret_cast<const h4*>(hsrc + m0 + 4);
      half_t h2 = hsrc[m0 + 8];
      hv[0] = (float)h0[0]; hv[1] = (float)h0[1]; hv[2] = (float)h0[2]; hv[3] = (float)h0[3];
      hv[4] = (float)h1[0]; hv[5] = (float)h1[1]; hv[6] = (float)h1[2]; hv[7] = (float)h1[3];
      hv[8] = (float)h2;
    }
    f2 a0 = {0.f, 0.f}, a1 = {0.f, 0.f}, a2 = {0.f, 0.f}, a3 = {0.f, 0.f};
#pragma unroll
    for (int t = 0; t < 6; ++t) {
      f2 dl = (f2){DEC_LO[2 * t + 1], DEC_LO[2 * t]};
      f2 dh = (f2){DEC_HI[2 * t + 1], DEC_HI[2 * t]};
      a0 += lv[t] * dl + hv[t] * dh;
      a1 += lv[1 + t] * dl + hv[1 + t] * dh;
      a2 += lv[2 + t] * dl + hv[2 + t] * dh;
      a3 += lv[3 + t] * dl + hv[3 + t] * dh;
    }
    *reinterpret_cast<float4*>(dst + 2 * m0)     = make_float4(a0.x, a0.y, a1.x, a1.y);
    *reinterpret_cast<float4*>(dst + 2 * m0 + 4) = make_float4(a2.x, a2.y, a3.x, a3.y);
    if (lane < 3) {  // pairs 256..258
      const int m = 256 + lane;
      float aE = 0.f, aO = 0.f;
#pragma unroll
      for (int t = 0; t < 6; ++t) {
        float lvv = cur[m + t];
        float hvv = (float)hsrc[m + t];
        aE += lvv * DEC_LO[2 * t + 1] + hvv * DEC_HI[2 * t + 1];
        aO += lvv * DEC_LO[2 * t]     + hvv * DEC_HI[2 * t];
      }
      *reinterpret_cast<f2*>(dst + 2 * m) = (f2){aE, aO};
    }
  }
  // s = 7: N=517, NP=512, 2x64 exact (no masks)
  {
    const half_t* hsrc = ws + (size_t)row * 520;  // hi0
    float* orow = out + (size_t)row * 1024;
#pragma unroll
    for (int q0 = 0; q0 < 128; q0 += 64) {
      const int m0 = 4 * (q0 + lane);
      float lv[9];
      {
        float4 a = *reinterpret_cast<const float4*>(dst + m0);
        float4 b = *reinterpret_cast<const float4*>(dst + m0 + 4);
        lv[0] = a.x; lv[1] = a.y; lv[2] = a.z; lv[3] = a.w;
        lv[4] = b.x; lv[5] = b.y; lv[6] = b.z; lv[7] = b.w;
        lv[8] = dst[m0 + 8];
      }
      float hv[9];
      {
        h4 h0 = *reinterpret_cast<const h4*>(hsrc + m0);
        h4 h1 = *reinterpret_cast<const h4*>(hsrc + m0 + 4);
        half_t h2 = hsrc[m0 + 8];
        hv[0] = (float)h0[0]; hv[1] = (float)h0[1]; hv[2] = (float)h0[2]; hv[3] = (float)h0[3];
        hv[4] = (float)h1[0]; hv[5] = (float)h1[1]; hv[6] = (float)h1[2]; hv[7] = (float)h1[3];
        hv[8] = (float)h2;
      }
      f2 a0 = {0.f, 0.f}, a1 = {0.f, 0.f}, a2 = {0.f, 0.f}, a3 = {0.f, 0.f};
#pragma unroll
      for (int t = 0; t < 6; ++t) {
        f2 dl = (f2){DEC_LO[2 * t + 1], DEC_LO[2 * t]};
        f2 dh = (f2){DEC_HI[2 * t + 1], DEC_HI[2 * t]};
        a0 += lv[t] * dl + hv[t] * dh;
        a1 += lv[1 + t] * dl + hv[1 + t] * dh;
        a2 += lv[2 + t] * dl + hv[2 + t] * dh;
        a3 += lv[3 + t] * dl + hv[3 + t] * dh;
      }
      *reinterpret_cast<float4*>(orow + 2 * m0)     = make_float4(a0.x, a0.y, a1.x, a1.y);
      *reinterpret_cast<float4*>(orow + 2 * m0 + 4) = make_float4(a2.x, a2.y, a3.x, a3.y);
    }
  }
}

// Both einsums, 2 batches per block: blocks 0..127 -> lo mix (w1), 128..255 -> hi mix (w2).
__global__ void mix_both(half_t* __restrict__ ws, const float* __restrict__ w1,
                         const float* __restrict__ w2) {
  __shared__ float s_in[2][896];
  const int which = blockIdx.x >> 7;
  const half_t* in = ws + (size_t)NROWS * (which ? 1112 : 1128);
  const float* w = which ? w2 : w1;
  half_t* out = ws + (size_t)NROWS * (which ? 1144 : 1160);
  int b0 = (blockIdx.x & 127) * 2;
  int t = threadIdx.x;  // 896 threads; t -> (i or o = t/14, x = t%14)
  int i = t / 14, xx = t % 14;
#pragma unroll
  for (int bb = 0; bb < 2; ++bb)
    s_in[bb][t] = (float)in[((size_t)(b0 + bb) * 64 + i) * 16 + xx];
  __syncthreads();
  float acc0 = 0.f, acc1 = 0.f;
#pragma unroll 8
  for (int k = 0; k < 64; ++k) {
    float wv = w[k * 896 + t];
    acc0 += s_in[0][k * 14 + xx] * wv;
    acc1 += s_in[1][k * 14 + xx] * wv;
  }
  out[((size_t)b0 * 64 + i) * 16 + xx] = (half_t)acc0;
  out[((size_t)(b0 + 1) * 64 + i) * 16 + xx] = (half_t)acc1;
}

extern "C" void kernel_launch(void* const* d_in, const int* in_sizes, int n_in,
                              void* d_out, int out_size, void* d_ws, size_t ws_size,
                              hipStream_t stream) {
  (void)in_sizes; (void)n_in; (void)out_size; (void)ws_size;
  const float* x  = (const float*)d_in[0];
  const float* w1 = (const float*)d_in[1];
  const float* w2 = (const float*)d_in[2];
  float* out = (float*)d_out;
  half_t* ws = (half_t*)d_ws;

  afb_fused<<<NROWS / WPB, 64 * WPB, 0, stream>>>(x, ws);
  mix_both<<<256, 896, 0, stream>>>(ws, w1, w2);
  sfb_fused<<<NROWS / WPB, 64 * WPB, 0, stream>>>(ws, out);
}

// Round 11
// 59.542 us; speedup vs baseline: 2.1539x; 1.0520x over previous
//
#include <hip/hip_runtime.h>

typedef float f2 __attribute__((ext_vector_type(2)));
typedef _Float16 half_t;
typedef _Float16 h4 __attribute__((ext_vector_type(4)));
typedef _Float16 h8 __attribute__((ext_vector_type(8)));

// Compile-time filter constants (fold to literals).
static constexpr float REC_LO[12] = {
  0.11154074335008017f, 0.4946238903983854f, 0.7511339080215775f, 0.3152503517092432f,
  -0.22626469396516913f, -0.12976686756709563f, 0.09750160558707936f, 0.02752286553001629f,
  -0.031582039318031156f, 0.0005538422009938016f, 0.004777257511010651f, -0.00107730108499558f };
static constexpr float REC_HI[12] = {
  -0.00107730108499558f, -0.004777257511010651f, 0.0005538422009938016f, 0.031582039318031156f,
  0.02752286553001629f, -0.09750160558707936f, -0.12976686756709563f, 0.22626469396516913f,
  0.3152503517092432f, -0.7511339080215775f, 0.4946238903983854f, -0.11154074335008017f };
static constexpr float DEC_LO[12] = {
  -0.00107730108499558f, 0.004777257511010651f, 0.0005538422009938016f, -0.031582039318031156f,
  0.02752286553001629f, 0.09750160558707936f, -0.12976686756709563f, -0.22626469396516913f,
  0.3152503517092432f, 0.7511339080215775f, 0.4946238903983854f, 0.11154074335008017f };
static constexpr float DEC_HI[12] = {
  -0.11154074335008017f, 0.4946238903983854f, -0.7511339080215775f, 0.3152503517092432f,
  0.22626469396516913f, -0.12976686756709563f, -0.09750160558707936f, 0.02752286553001629f,
  0.031582039318031156f, 0.0005538422009938016f, -0.004777257511010651f, -0.00107730108499558f };

#define NROWS 16384
#define WPB 4  // waves (= rows) per block

// ws layout in HALF elements, per-row strides padded to x8 for 16B alignment:
//  hi0 520@0, hi1 264@520, hi2 144@784, hi3 80@928, hi4 48@1008, hi5 32@1056,
//  hi6 24@1088, hi7 16@1112, loFinal 16@1128, hm 16@1144, loMixed 16@1160.

// ---------------- Fused 8-level analysis ----------------
// Phase 1 (each wave, own row): L0 direct-from-global + tail + pads, L1 + pads.
// Phase 2: levels 2..7 chunk-parallel across ALL 4 waves: group g (16 lanes)
// handles row g&3, chunk quarter g>>2 (q = (g>>2)*16+l16; NCH<=35<64 -> one
// body per level). Waves with empty quarters skip via execz. Barriers only
// where cross-wave deps exist (j=2,3).
__global__ __launch_bounds__(256) void afb_fused(const float* __restrict__ x,
                                                 half_t* __restrict__ ws) {
  __shared__ float sA[WPB][548];
  __shared__ float sB[WPB][296];
  constexpr int LENS[9] = {1024, 517, 264, 137, 74, 42, 26, 18, 14};
  constexpr int HSTR[8] = {520, 264, 144, 80, 48, 32, 24, 16};
  constexpr int HOFF[8] = {0, 520, 784, 928, 1008, 1056, 1088, 1112};
  const int wid = threadIdx.x >> 6;
  const int lane = threadIdx.x & 63;
  const int row = blockIdx.x * WPB + wid;
  float* bufA = sA[wid];
  float* bufB = sB[wid];
  const float* xrow = x + (size_t)row * 1024;
  half_t* hi0 = ws + (size_t)row * 520;

  // ---- Level 0: outputs 0..511, one full-wave pass ----
  {
    const int q = lane;
    const int base = (q == 0) ? 0 : 16 * q - 12;
    float xv[28];
#pragma unroll
    for (int r = 0; r < 7; ++r) {
      float4 v = *reinterpret_cast<const float4*>(xrow + base + 4 * r);
      xv[4 * r] = v.x; xv[4 * r + 1] = v.y; xv[4 * r + 2] = v.z; xv[4 * r + 3] = v.w;
    }
    float w[26];
    if (q == 0) {
#pragma unroll
      for (int e = 0; e < 26; ++e) w[e] = xv[e < 10 ? 9 - e : e - 10];
    } else {
#pragma unroll
      for (int e = 0; e < 26; ++e) w[e] = xv[2 + e];
    }
    f2 a[8];
#pragma unroll
    for (int d = 0; d < 8; ++d) a[d] = (f2){0.f, 0.f};
#pragma unroll
    for (int k = 0; k < 12; ++k) {
      f2 c = (f2){REC_LO[k], REC_HI[k]};
#pragma unroll
      for (int d = 0; d < 8; ++d) a[d] += w[2 * d + k] * c;
    }
#pragma unroll
    for (int d = 0; d < 4; ++d)
      *reinterpret_cast<f2*>(bufA + 14 + 8 * q + 2 * d) = (f2){a[2 * d].x, a[2 * d + 1].x};
    h8 hh;
#pragma unroll
    for (int d = 0; d < 8; ++d) hh[d] = (half_t)a[d].y;
    *reinterpret_cast<h8*>(hi0 + 8 * q) = hh;
  }
  // ---- Level 0 tail: outputs 512..516 on lanes 0..4 ----
  if (lane < 5) {
    const int i0 = 1014 + 2 * lane;
    float acL = 0.f, acH = 0.f;
#pragma unroll
    for (int k = 0; k < 12; ++k) {
      int idx = i0 + k;
      idx = min(idx, 2047 - idx);
      float v = xrow[idx];
      acL += v * REC_LO[k];
      acH += v * REC_HI[k];
    }
    bufA[14 + 512 + lane] = acL;
    hi0[512 + lane] = (half_t)acH;
  }
  if (lane < 21) {  // pads for level-1 input
    int d, s;
    if (lane < 10) { d = 13 - lane; s = 14 + lane; }
    else { int k = lane - 10; d = 14 + 517 + k; s = 14 + 516 - k; }
    bufA[d] = bufA[s];
  }

  // ---- Level 1: chunk-8, 33 lanes (264 = 33*8 exact) ----
  if (lane < 33) {
    const float* pp = bufA + 16 * lane + 4;
    float xv[28];
#pragma unroll
    for (int r = 0; r < 7; ++r) {
      float4 v = *reinterpret_cast<const float4*>(pp + 4 * r);
      xv[4 * r] = v.x; xv[4 * r + 1] = v.y; xv[4 * r + 2] = v.z; xv[4 * r + 3] = v.w;
    }
    f2 a[8];
#pragma unroll
    for (int d = 0; d < 8; ++d) a[d] = (f2){0.f, 0.f};
#pragma unroll
    for (int k = 0; k < 12; ++k) {
      f2 c = (f2){REC_LO[k], REC_HI[k]};
#pragma unroll
      for (int d = 0; d < 8; ++d) a[d] += xv[2 * d + k] * c;
    }
#pragma unroll
    for (int d = 0; d < 4; ++d)
      *reinterpret_cast<f2*>(bufB + 14 + 8 * lane + 2 * d) = (f2){a[2 * d].x, a[2 * d + 1].x};
    h8 hh;
#pragma unroll
    for (int d = 0; d < 8; ++d) hh[d] = (half_t)a[d].y;
    *reinterpret_cast<h8*>(ws + (size_t)NROWS * 520 + (size_t)row * 264 + 8 * lane) = hh;
  }
  if (lane < 21) {  // pads for level-2 input
    int d, s;
    if (lane < 10) { d = 13 - lane; s = 14 + lane; }
    else { int k = lane - 10; d = 14 + 264 + k; s = 14 + 263 - k; }
    bufB[d] = bufB[s];
  }

  __syncthreads();

  // ---- Phase 2: levels 2..7, chunk-parallel across all 4 waves ----
  const int gid = threadIdx.x >> 4;
  const int l16 = threadIdx.x & 15;
  const int sub2 = gid & 3;                 // row within block
  const int q2 = ((gid >> 2) << 4) + l16;   // chunk index 0..63
  const int prow = blockIdx.x * WPB + sub2;
  float* cur = sB[sub2];
  float* dst = sA[sub2];
#pragma unroll
  for (int j = 2; j < 8; ++j) {
    const int outN = LENS[j + 1];
    const int NCH = (outN + 3) / 4;   // 35,19,11,7,5,4
    half_t* hiRow = ws + (size_t)NROWS * HOFF[j] + (size_t)prow * HSTR[j];
    if (q2 < NCH) {
      const float* pp = cur + 8 * q2 + 4;
      float xv[20];
#pragma unroll
      for (int r = 0; r < 5; ++r) {
        float4 v = *reinterpret_cast<const float4*>(pp + 4 * r);
        xv[4 * r] = v.x; xv[4 * r + 1] = v.y; xv[4 * r + 2] = v.z; xv[4 * r + 3] = v.w;
      }
      f2 a0 = {0.f, 0.f}, a1 = {0.f, 0.f}, a2 = {0.f, 0.f}, a3 = {0.f, 0.f};
#pragma unroll
      for (int k = 0; k < 12; ++k) {
        f2 c = (f2){REC_LO[k], REC_HI[k]};
        a0 += xv[k] * c; a1 += xv[2 + k] * c; a2 += xv[4 + k] * c; a3 += xv[6 + k] * c;
      }
      if (j < 7) {
        *reinterpret_cast<f2*>(dst + 14 + 4 * q2) = (f2){a0.x, a1.x};
        *reinterpret_cast<f2*>(dst + 16 + 4 * q2) = (f2){a2.x, a3.x};
      } else {
        h4 hl; hl[0] = (half_t)a0.x; hl[1] = (half_t)a1.x; hl[2] = (half_t)a2.x; hl[3] = (half_t)a3.x;
        *reinterpret_cast<h4*>(ws + (size_t)NROWS * 1128 + (size_t)prow * 16 + 4 * q2) = hl;
      }
      h4 hh; hh[0] = (half_t)a0.y; hh[1] = (half_t)a1.y; hh[2] = (half_t)a2.y; hh[3] = (half_t)a3.y;
      *reinterpret_cast<h4*>(hiRow + 4 * q2) = hh;
    }
    if (j < 7) {
      // j=2,3: right-pad source / next-level reads span other waves' writes.
      if (j < 4) __syncthreads();
      if (gid < 4) {  // wave-0 group g pads row g (sub2 == gid here)
        if (l16 < 10) dst[13 - l16] = dst[14 + l16];
        if (l16 < 11) dst[14 + outN + l16] = dst[14 + outN - 1 - l16];
      }
      if (j < 4) __syncthreads();
      float* t = cur; cur = dst; dst = t;
    }
  }
}

// ---------------- Fused 8-level synthesis ----------------
// Phase 1: s=0..5 chunk-parallel across ALL 4 waves (same group mapping as afb
// phase 2; PCH = 3,4,6,10,18,33 <= 64 -> one body per level). Barriers after
// s=3 and s=4 (first levels where waves 1/2 read other waves' writes).
// Phase 2 (all waves, own row): s=6 (64 chunks + 3-lane tail), s=7 (2x64 exact).
// hi always read directly from global fp16.
__global__ __launch_bounds__(256) void sfb_fused(const half_t* __restrict__ ws,
                                                 float* __restrict__ out) {
  __shared__ float sP[WPB][280];  // y0,y2,y4,y6 (max read idx 267)
  __shared__ float sQ[WPB][544];  // y1,y3,y5,y7 (max write idx 517)
  const int wid = threadIdx.x >> 6;
  const int lane = threadIdx.x & 63;

  {
    constexpr int LENSY[6] = {14, 18, 26, 42, 74, 137};
    constexpr int HSOFF[6] = {1144, 1088, 1056, 1008, 928, 784};  // hm, hi6..hi2
    constexpr int HSSTR[6] = {16, 24, 32, 48, 80, 144};
    const int gid = threadIdx.x >> 4;
    const int l16 = threadIdx.x & 15;
    const int sub = gid & 3;
    const int q1 = ((gid >> 2) << 4) + l16;   // 0..63
    const int prow = blockIdx.x * WPB + sub;
    float* cur = sP[sub];
    float* dst = sQ[sub];
    if (gid < 4 && l16 < 2) {  // y0 = loMixed for row gid (14 valid; 14,15 ghost-only)
      h8 v = *reinterpret_cast<const h8*>(ws + (size_t)NROWS * 1160 + (size_t)prow * 16 + 8 * l16);
      *reinterpret_cast<float4*>(cur + 8 * l16) =
          make_float4((float)v[0], (float)v[1], (float)v[2], (float)v[3]);
      *reinterpret_cast<float4*>(cur + 8 * l16 + 4) =
          make_float4((float)v[4], (float)v[5], (float)v[6], (float)v[7]);
    }
#pragma unroll
    for (int s = 0; s < 6; ++s) {
      const int N = LENSY[s];
      const int NP = N - 5;
      const int PCH = (NP + 3) / 4;   // 3,4,6,10,18,33
      const half_t* hsrc = ws + (size_t)NROWS * HSOFF[s] + (size_t)prow * HSSTR[s];
      if (q1 < PCH) {
        const int m0 = 4 * q1;
        float lv[9];
        {
          float4 a = *reinterpret_cast<const float4*>(cur + m0);
          float4 b = *reinterpret_cast<const float4*>(cur + m0 + 4);
          lv[0] = a.x; lv[1] = a.y; lv[2] = a.z; lv[3] = a.w;
          lv[4] = b.x; lv[5] = b.y; lv[6] = b.z; lv[7] = b.w;
          lv[8] = cur[m0 + 8];
        }
        float hv[9];
        {
          h4 h0 = *reinterpret_cast<const h4*>(hsrc + m0);
          h4 h1 = *reinterpret_cast<const h4*>(hsrc + m0 + 4);
          half_t h2 = hsrc[m0 + 8];
          hv[0] = (float)h0[0]; hv[1] = (float)h0[1]; hv[2] = (float)h0[2]; hv[3] = (float)h0[3];
          hv[4] = (float)h1[0]; hv[5] = (float)h1[1]; hv[6] = (float)h1[2]; hv[7] = (float)h1[3];
          hv[8] = (float)h2;
        }
        f2 a0 = {0.f, 0.f}, a1 = {0.f, 0.f}, a2 = {0.f, 0.f}, a3 = {0.f, 0.f};
#pragma unroll
        for (int t = 0; t < 6; ++t) {
          f2 dl = (f2){DEC_LO[2 * t + 1], DEC_LO[2 * t]};
          f2 dh = (f2){DEC_HI[2 * t + 1], DEC_HI[2 * t]};
          a0 += lv[t] * dl + hv[t] * dh;
          a1 += lv[1 + t] * dl + hv[1 + t] * dh;
          a2 += lv[2 + t] * dl + hv[2 + t] * dh;
          a3 += lv[3 + t] * dl + hv[3 + t] * dh;
        }
        *reinterpret_cast<float4*>(dst + 2 * m0)     = make_float4(a0.x, a0.y, a1.x, a1.y);
        *reinterpret_cast<float4*>(dst + 2 * m0 + 4) = make_float4(a2.x, a2.y, a3.x, a3.y);
      }
      if (s == 3 || s == 4) __syncthreads();  // next level crosses wave boundaries
      float* t = cur; cur = dst; dst = t;
    }
    // after 6 swaps: y6 lives in sP[sub]
  }
  __syncthreads();

  // ---- Phase 2: all waves, own row ----
  const int row = blockIdx.x * WPB + wid;
  float* cur = sP[wid];
  float* dst = sQ[wid];
  // s = 6: N=264, NP=259: one unmasked 64-chunk pass (pairs 0..255) + 3-lane tail
  {
    const half_t* hsrc = ws + (size_t)NROWS * 520 + (size_t)row * 264;  // hi1
    const int m0 = 4 * lane;
    float lv[9];
    {
      float4 a = *reinterpret_cast<const float4*>(cur + m0);
      float4 b = *reinterpret_cast<const float4*>(cur + m0 + 4);
      lv[0] = a.x; lv[1] = a.y; lv[2] = a.z; lv[3] = a.w;
      lv[4] = b.x; lv[5] = b.y; lv[6] = b.z; lv[7] = b.w;
      lv[8] = cur[m0 + 8];
    }
    float hv[9];
    {
      h4 h0 = *reinterpret_cast<const h4*>(hsrc + m0);
      h4 h1 = *reinterpret_cast<const h4*>(hsrc + m0 + 4);
      half_t h2 = hsrc[m0 + 8];
      hv[0] = (float)h0[0]; hv[1] = (float)h0[1]; hv[2] = (float)h0[2]; hv[3] = (float)h0[3];
      hv[4] = (float)h1[0]; hv[5] = (float)h1[1]; hv[6] = (float)h1[2]; hv[7] = (float)h1[3];
      hv[8] = (float)h2;
    }
    f2 a0 = {0.f, 0.f}, a1 = {0.f, 0.f}, a2 = {0.f, 0.f}, a3 = {0.f, 0.f};
#pragma unroll
    for (int t = 0; t < 6; ++t) {
      f2 dl = (f2){DEC_LO[2 * t + 1], DEC_LO[2 * t]};
      f2 dh = (f2){DEC_HI[2 * t + 1], DEC_HI[2 * t]};
      a0 += lv[t] * dl + hv[t] * dh;
      a1 += lv[1 + t] * dl + hv[1 + t] * dh;
      a2 += lv[2 + t] * dl + hv[2 + t] * dh;
      a3 += lv[3 + t] * dl + hv[3 + t] * dh;
    }
    *reinterpret_cast<float4*>(dst + 2 * m0)     = make_float4(a0.x, a0.y, a1.x, a1.y);
    *reinterpret_cast<float4*>(dst + 2 * m0 + 4) = make_float4(a2.x, a2.y, a3.x, a3.y);
    if (lane < 3) {  // pairs 256..258
      const int m = 256 + lane;
      float aE = 0.f, aO = 0.f;
#pragma unroll
      for (int t = 0; t < 6; ++t) {
        float lvv = cur[m + t];
        float hvv = (float)hsrc[m + t];
        aE += lvv * DEC_LO[2 * t + 1] + hvv * DEC_HI[2 * t + 1];
        aO += lvv * DEC_LO[2 * t]     + hvv * DEC_HI[2 * t];
      }
      *reinterpret_cast<f2*>(dst + 2 * m) = (f2){aE, aO};
    }
  }
  // s = 7: N=517, NP=512, 2x64 exact (no masks)
  {
    const half_t* hsrc = ws + (size_t)row * 520;  // hi0
    float* orow = out + (size_t)row * 1024;
#pragma unroll
    for (int q0 = 0; q0 < 128; q0 += 64) {
      const int m0 = 4 * (q0 + lane);
      float lv[9];
      {
        float4 a = *reinterpret_cast<const float4*>(dst + m0);
        float4 b = *reinterpret_cast<const float4*>(dst + m0 + 4);
        lv[0] = a.x; lv[1] = a.y; lv[2] = a.z; lv[3] = a.w;
        lv[4] = b.x; lv[5] = b.y; lv[6] = b.z; lv[7] = b.w;
        lv[8] = dst[m0 + 8];
      }
      float hv[9];
      {
        h4 h0 = *reinterpret_cast<const h4*>(hsrc + m0);
        h4 h1 = *reinterpret_cast<const h4*>(hsrc + m0 + 4);
        half_t h2 = hsrc[m0 + 8];
        hv[0] = (float)h0[0]; hv[1] = (float)h0[1]; hv[2] = (float)h0[2]; hv[3] = (float)h0[3];
        hv[4] = (float)h1[0]; hv[5] = (float)h1[1]; hv[6] = (float)h1[2]; hv[7] = (float)h1[3];
        hv[8] = (float)h2;
      }
      f2 a0 = {0.f, 0.f}, a1 = {0.f, 0.f}, a2 = {0.f, 0.f}, a3 = {0.f, 0.f};
#pragma unroll
      for (int t = 0; t < 6; ++t) {
        f2 dl = (f2){DEC_LO[2 * t + 1], DEC_LO[2 * t]};
        f2 dh = (f2){DEC_HI[2 * t + 1], DEC_HI[2 * t]};
        a0 += lv[t] * dl + hv[t] * dh;
        a1 += lv[1 + t] * dl + hv[1 + t] * dh;
        a2 += lv[2 + t] * dl + hv[2 + t] * dh;
        a3 += lv[3 + t] * dl + hv[3 + t] * dh;
      }
      *reinterpret_cast<float4*>(orow + 2 * m0)     = make_float4(a0.x, a0.y, a1.x, a1.y);
      *reinterpret_cast<float4*>(orow + 2 * m0 + 4) = make_float4(a2.x, a2.y, a3.x, a3.y);
    }
  }
}

// Both einsums, 2 batches per block: blocks 0..127 -> lo mix (w1), 128..255 -> hi mix (w2).
__global__ void mix_both(half_t* __restrict__ ws, const float* __restrict__ w1,
                         const float* __restrict__ w2) {
  __shared__ float s_in[2][896];
  const int which = blockIdx.x >> 7;
  const half_t* in = ws + (size_t)NROWS * (which ? 1112 : 1128);
  const float* w = which ? w2 : w1;
  half_t* out = ws + (size_t)NROWS * (which ? 1144 : 1160);
  int b0 = (blockIdx.x & 127) * 2;
  int t = threadIdx.x;  // 896 threads; t -> (i or o = t/14, x = t%14)
  int i = t / 14, xx = t % 14;
#pragma unroll
  for (int bb = 0; bb < 2; ++bb)
    s_in[bb][t] = (float)in[((size_t)(b0 + bb) * 64 + i) * 16 + xx];
  __syncthreads();
  float acc0 = 0.f, acc1 = 0.f;
#pragma unroll 8
  for (int k = 0; k < 64; ++k) {
    float wv = w[k * 896 + t];
    acc0 += s_in[0][k * 14 + xx] * wv;
    acc1 += s_in[1][k * 14 + xx] * wv;
  }
  out[((size_t)b0 * 64 + i) * 16 + xx] = (half_t)acc0;
  out[((size_t)(b0 + 1) * 64 + i) * 16 + xx] = (half_t)acc1;
}

extern "C" void kernel_launch(void* const* d_in, const int* in_sizes, int n_in,
                              void* d_out, int out_size, void* d_ws, size_t ws_size,
                              hipStream_t stream) {
  (void)in_sizes; (void)n_in; (void)out_size; (void)ws_size;
  const float* x  = (const float*)d_in[0];
  const float* w1 = (const float*)d_in[1];
  const float* w2 = (const float*)d_in[2];
  float* out = (float*)d_out;
  half_t* ws = (half_t*)d_ws;

  afb_fused<<<NROWS / WPB, 64 * WPB, 0, stream>>>(x, ws);
  mix_both<<<256, 896, 0, stream>>>(ws, w1, w2);
  sfb_fused<<<NROWS / WPB, 64 * WPB, 0, stream>>>(ws, out);
}